// Round 9
// baseline (653.421 us; speedup 1.0000x reference)
//
#include <hip/hip_runtime.h>
#include <hip/hip_bf16.h>

#define Bn 64
#define Tn 512
#define En 128
#define Hn 64
#define Gn 256   // 4*H
#define Cn 20

typedef float f32x2 __attribute__((ext_vector_type(2)));

__device__ __forceinline__ float sigf(float x)      { return 1.f/(1.f+__expf(-x)); }
__device__ __forceinline__ float tanhfast(float x)  { return 2.f/(1.f+__expf(-2.f*x)) - 1.f; }

// ---------------------------------------------------------------------------
// Kernel A: Z0[b*T+t][j] = (word_emb[ids[b,t]] + pos_emb[t]) @ Wx_b0 + b_b0
// ---------------------------------------------------------------------------
__global__ __launch_bounds__(256, 1) void emb_proj_kernel(
    const int* __restrict__ x, const float* __restrict__ word_emb,
    const float* __restrict__ pos_emb, const float* __restrict__ wx,
    const float* __restrict__ bias, float* __restrict__ z0)
{
  __shared__ float emb[64][En];     // 32 KB
  __shared__ float wxl[32][Gn];     // 32 KB
  const int tid  = threadIdx.x;
  const int row0 = blockIdx.x * 64;

  #pragma unroll
  for (int it = 0; it < 8; ++it) {
    int idx = it*256 + tid;
    int rr  = idx >> 5;
    int e4  = (idx & 31) << 2;
    int r   = row0 + rr;
    int b   = r >> 9;
    int t   = r & (Tn-1);
    int id  = x[b*3*Tn + t];
    float4 we = *reinterpret_cast<const float4*>(&word_emb[(size_t)id*En + e4]);
    float4 pe = *reinterpret_cast<const float4*>(&pos_emb[(size_t)t*En + e4]);
    *reinterpret_cast<float4*>(&emb[rr][e4]) =
        make_float4(we.x+pe.x, we.y+pe.y, we.z+pe.z, we.w+pe.w);
  }

  const int jc = tid & 63;
  const int rg = tid >> 6;
  float acc[16][4];
  float4 bb = *reinterpret_cast<const float4*>(&bias[jc*4]);
  #pragma unroll
  for (int r = 0; r < 16; ++r) { acc[r][0]=bb.x; acc[r][1]=bb.y; acc[r][2]=bb.z; acc[r][3]=bb.w; }

  for (int ec = 0; ec < 4; ++ec) {
    __syncthreads();
    #pragma unroll
    for (int it = 0; it < 8; ++it) {
      int idx = it*256 + tid;
      int ee  = idx >> 6;
      int j4  = (idx & 63) << 2;
      *reinterpret_cast<float4*>(&wxl[ee][j4]) =
          *reinterpret_cast<const float4*>(&wx[(size_t)(ec*32+ee)*Gn + j4]);
    }
    __syncthreads();
    for (int ee = 0; ee < 32; ++ee) {
      float4 w = *reinterpret_cast<const float4*>(&wxl[ee][jc*4]);
      #pragma unroll
      for (int r = 0; r < 16; ++r) {
        float xv = emb[rg*16+r][ec*32+ee];
        acc[r][0] = fmaf(xv, w.x, acc[r][0]);
        acc[r][1] = fmaf(xv, w.y, acc[r][1]);
        acc[r][2] = fmaf(xv, w.z, acc[r][2]);
        acc[r][3] = fmaf(xv, w.w, acc[r][3]);
      }
    }
  }
  #pragma unroll
  for (int r = 0; r < 16; ++r) {
    size_t row = (size_t)row0 + rg*16 + r;
    *reinterpret_cast<float4*>(&z0[row*Gn + jc*4]) =
        make_float4(acc[r][0], acc[r][1], acc[r][2], acc[r][3]);
  }
}

// ---------------------------------------------------------------------------
// Kernel A2: ZX1[b*T+t][j] = hb0[b,t,:] @ Wx_b1 + b_b1
// ---------------------------------------------------------------------------
__global__ __launch_bounds__(256, 1) void zx1_gemm_kernel(
    const float* __restrict__ hb0, const float* __restrict__ wx,
    const float* __restrict__ bias, float* __restrict__ zx1)
{
  __shared__ float xl[64][Hn];
  __shared__ float wl[32][Gn];
  const int tid  = threadIdx.x;
  const int row0 = blockIdx.x * 64;

  #pragma unroll
  for (int it = 0; it < 4; ++it) {
    int idx = it*256 + tid;
    int rr  = idx >> 4;
    int e4  = (idx & 15) << 2;
    *reinterpret_cast<float4*>(&xl[rr][e4]) =
        *reinterpret_cast<const float4*>(&hb0[((size_t)row0+rr)*Hn + e4]);
  }

  const int jc = tid & 63;
  const int rg = tid >> 6;
  float acc[16][4];
  float4 bb = *reinterpret_cast<const float4*>(&bias[jc*4]);
  #pragma unroll
  for (int r = 0; r < 16; ++r) { acc[r][0]=bb.x; acc[r][1]=bb.y; acc[r][2]=bb.z; acc[r][3]=bb.w; }

  for (int kc = 0; kc < 2; ++kc) {
    __syncthreads();
    #pragma unroll
    for (int it = 0; it < 8; ++it) {
      int idx = it*256 + tid;
      int kk  = idx >> 6;
      int j4  = (idx & 63) << 2;
      *reinterpret_cast<float4*>(&wl[kk][j4]) =
          *reinterpret_cast<const float4*>(&wx[(size_t)(kc*32+kk)*Gn + j4]);
    }
    __syncthreads();
    for (int kk = 0; kk < 32; ++kk) {
      float4 w = *reinterpret_cast<const float4*>(&wl[kk][jc*4]);
      #pragma unroll
      for (int r = 0; r < 16; ++r) {
        float xv = xl[rg*16+r][kc*32+kk];
        acc[r][0] = fmaf(xv, w.x, acc[r][0]);
        acc[r][1] = fmaf(xv, w.y, acc[r][1]);
        acc[r][2] = fmaf(xv, w.z, acc[r][2]);
        acc[r][3] = fmaf(xv, w.w, acc[r][3]);
      }
    }
  }
  #pragma unroll
  for (int r = 0; r < 16; ++r) {
    size_t row = (size_t)row0 + rg*16 + r;
    *reinterpret_cast<float4*>(&zx1[row*Gn + jc*4]) =
        make_float4(acc[r][0], acc[r][1], acc[r][2], acc[r][3]);
  }
}

// ---------------------------------------------------------------------------
// Recurrence: 256 threads / 4 waves per batch element. Thread tid owns gate
// column tid. Weights live in 32 individually-NAMED f32x2 SSA variables
// (no array => cannot be allocated to scratch; R6/R8's VGPR_Count=52 proved
// the array forms were scratch-resident and re-loaded every step). 4
// accumulators break the pk_fma dependency chain. One raw s_barrier per
// step (lgkm-only drain); in-loop VMEM is inline asm with counted vmcnt.
// ---------------------------------------------------------------------------
#define WAVE_BARRIER()                                        \
  do {                                                        \
    asm volatile("s_waitcnt lgkmcnt(0)" ::: "memory");        \
    __builtin_amdgcn_sched_barrier(0);                        \
    __builtin_amdgcn_s_barrier();                             \
    __builtin_amdgcn_sched_barrier(0);                        \
  } while (0)

#define PK_FMA(acc, hp, wp) \
  asm("v_pk_fma_f32 %0, %1, %2, %0" : "+v"(acc) : "v"(hp), "v"(wp))

#define PLOAD(dst, t_)                                                      \
  { const float* pp_ = zr + (size_t)(t_)*Gn + tid;                          \
    asm volatile("global_load_dword %0, %1, off" : "=v"(dst) : "v"(pp_)); }

// named weight pair decl: rows 4k..4k+3 of Wh, this thread's column
#define DECLW(k)                                                            \
  f32x2 w##k##a = {wh[(size_t)(4*(k)+0)*Gn + tid],                          \
                   wh[(size_t)(4*(k)+1)*Gn + tid]};                         \
  f32x2 w##k##b = {wh[(size_t)(4*(k)+2)*Gn + tid],                          \
                   wh[(size_t)(4*(k)+3)*Gn + tid]};

// one 4-wide K-slice: h[4k..4k+3] (LDS b128 broadcast) * named weights
#define FMAK(k, ACC)                                                        \
  { float4 hv = *reinterpret_cast<const float4*>(&h_own[wv][(k)*4]);        \
    f32x2 h01 = {hv.x, hv.y}, h23 = {hv.z, hv.w};                           \
    PK_FMA(ACC, h01, w##k##a);                                              \
    PK_FMA(ACC, h23, w##k##b); }

template<bool IS_B0>
__global__ __launch_bounds__(256, 1) void lstm_fast(
    const int* __restrict__ x, const float* __restrict__ z,
    const float* __restrict__ wh, float* __restrict__ hb0,
    const float* __restrict__ dw, const float* __restrict__ db,
    float* __restrict__ out)
{
  const int b   = blockIdx.x;
  const int tid = threadIdx.x;
  const int wv  = tid >> 6;
  const int l   = tid & 63;

  __shared__ __align__(16) float z_s[2][Gn];
  __shared__ __align__(16) float h_own[4][Hn];   // per-wave private h copy
  __shared__ float sm[2][32];
  __shared__ int slen;

  if (tid == 0) slen = 0;
  __syncthreads();
  {
    int m0 = x[b*3*Tn + 2*Tn + tid];
    int m1 = x[b*3*Tn + 2*Tn + 256 + tid];
    atomicAdd(&slen, m0 + m1);
  }
  // 32 named f32x2 weight pairs -- forced VGPR residency
  DECLW(0)  DECLW(1)  DECLW(2)  DECLW(3)
  DECLW(4)  DECLW(5)  DECLW(6)  DECLW(7)
  DECLW(8)  DECLW(9)  DECLW(10) DECLW(11)
  DECLW(12) DECLW(13) DECLW(14) DECLW(15)
  h_own[wv][l] = 0.f;
  __syncthreads();
  const int len = slen;             // in [T/4, T]; mask is 1s then 0s

  const float* zr   = z   + (size_t)b*Tn*Gn;
  float*       hout = hb0 + (size_t)b*Tn*Hn;
  float c = 0.f, h = 0.f;

  if (IS_B0) {
    // rows [len, T-1] of hout must be 0 (b1 consumes them)
    for (int r = len + (tid >> 4); r < Tn; r += 16)
      *reinterpret_cast<float4*>(&hout[(size_t)r*Hn + (tid & 15)*4]) =
          make_float4(0.f, 0.f, 0.f, 0.f);
  }

  // depth-4 prefetch into fixed named regs, drained ONCE before the loop.
  float zp0, zp1, zp2, zp3;
  PLOAD(zp0, IS_B0 ? len-1 : Tn-len);
  PLOAD(zp1, IS_B0 ? len-2 : Tn-len+1);
  PLOAD(zp2, IS_B0 ? len-3 : Tn-len+2);
  PLOAD(zp3, IS_B0 ? len-4 : Tn-len+3);
  asm volatile("s_waitcnt vmcnt(0)" ::: "memory");
  __builtin_amdgcn_sched_barrier(0);

#define STEP(s_, ZREG)                                                       \
  {                                                                          \
    if (IS_B0) asm volatile("s_waitcnt vmcnt(7)" ::: "memory");              \
    else       asm volatile("s_waitcnt vmcnt(3)" ::: "memory");              \
    __builtin_amdgcn_sched_barrier(0);                                       \
    f32x2 A0 = {ZREG, 0.f}, A1 = {0.f,0.f}, A2 = {0.f,0.f}, A3 = {0.f,0.f};  \
    FMAK(0,A0)  FMAK(1,A1)  FMAK(2,A2)  FMAK(3,A3)                           \
    FMAK(4,A0)  FMAK(5,A1)  FMAK(6,A2)  FMAK(7,A3)                           \
    FMAK(8,A0)  FMAK(9,A1)  FMAK(10,A2) FMAK(11,A3)                          \
    FMAK(12,A0) FMAK(13,A1) FMAK(14,A2) FMAK(15,A3)                          \
    z_s[(s_)&1][tid] = ((A0[0]+A0[1])+(A1[0]+A1[1]))                         \
                     + ((A2[0]+A2[1])+(A3[0]+A3[1]));                        \
    { /* issue load for step s_+4 early (max slack) */                       \
      int tn_ = IS_B0 ? (len-5-(s_)) : (Tn-len+(s_)+4);                      \
      tn_ = tn_ < 0 ? 0 : (tn_ > Tn-1 ? Tn-1 : tn_);                         \
      const float* pp_ = zr + (size_t)tn_*Gn + tid;                          \
      asm volatile("global_load_dword %0, %1, off" : "=v"(ZREG) : "v"(pp_)); \
    }                                                                        \
    WAVE_BARRIER();                                                          \
    float g0 = z_s[(s_)&1][l],      g1 = z_s[(s_)&1][Hn+l];                  \
    float g2 = z_s[(s_)&1][2*Hn+l], g3 = z_s[(s_)&1][3*Hn+l];                \
    float ig = sigf(g0), fg = sigf(g1);                                      \
    float gg = tanhfast(g2), og = sigf(g3);                                  \
    float cn_ = fmaf(fg, c, ig*gg);                                          \
    float hn_ = og * tanhfast(cn_);                                          \
    bool act_ = (s_) < len;                                                  \
    c = act_ ? cn_ : c;                                                      \
    h = act_ ? hn_ : h;                                                      \
    h_own[wv][l] = h;                                                        \
    if (IS_B0) {                                                             \
      int ts_ = len-1-(s_); ts_ = ts_ < 0 ? 0 : ts_;                         \
      float* sp_ = hout + (size_t)ts_*Hn + l;                                \
      asm volatile("global_store_dword %0, %1, off" :: "v"(sp_), "v"(h));    \
    }                                                                        \
  }

  const int lenr = (len + 3) & ~3;
  for (int s = 0; s < lenr; s += 4) {
    STEP(s+0, zp0);
    STEP(s+1, zp1);
    STEP(s+2, zp2);
    STEP(s+3, zp3);
  }
#undef STEP

  // drain asm VMEM; keep async-written regs alive past the drain (R5 lesson)
  asm volatile("s_waitcnt vmcnt(0)" ::: "memory");
  asm volatile("" :: "v"(zp0), "v"(zp1), "v"(zp2), "v"(zp3));
  __builtin_amdgcn_sched_barrier(0);

  if (!IS_B0) {
    // head: logits (C=20) + softmax; wave-0 lanes, wave-synchronous LDS
    if (tid < Cn) {
      float lg = db[tid];
      #pragma unroll
      for (int k = 0; k < Hn; ++k) lg = fmaf(h_own[0][k], dw[k*Cn + tid], lg);
      sm[0][tid] = lg;
    }
    if (tid < Cn) {
      float m = sm[0][0];
      #pragma unroll
      for (int k = 1; k < Cn; ++k) m = fmaxf(m, sm[0][k]);
      float e = __expf(sm[0][tid] - m);
      sm[1][tid] = e;
      float ssum = 0.f;
      #pragma unroll
      for (int k = 0; k < Cn; ++k) ssum += sm[1][k];
      out[b*Cn + tid] = e / ssum;
    }
  }
}

// ---------------------------------------------------------------------------
extern "C" void kernel_launch(void* const* d_in, const int* in_sizes, int n_in,
                              void* d_out, int out_size, void* d_ws, size_t ws_size,
                              hipStream_t stream)
{
  const int*   x        = (const int*)  d_in[0];
  const float* word_emb = (const float*)d_in[1];
  const float* pos_emb  = (const float*)d_in[2];
  // forward-branch weights d_in[3..8] are dead code in the reference
  const float* wx_b0    = (const float*)d_in[9];
  const float* wh_b0    = (const float*)d_in[10];
  const float* b_b0     = (const float*)d_in[11];
  const float* wx_b1    = (const float*)d_in[12];
  const float* wh_b1    = (const float*)d_in[13];
  const float* b_b1     = (const float*)d_in[14];
  const float* dw       = (const float*)d_in[15];
  const float* db       = (const float*)d_in[16];
  float* out = (float*)d_out;

  float* z0  = (float*)d_ws;                    // B*T*256 f32 = 33.5 MB (reused as ZX1)
  float* hb0 = z0 + (size_t)Bn*Tn*Gn;           // B*T*64  f32 =  8.4 MB

  emb_proj_kernel<<<dim3((Bn*Tn)/64), dim3(256), 0, stream>>>(
      x, word_emb, pos_emb, wx_b0, b_b0, z0);
  lstm_fast<true><<<dim3(Bn), dim3(256), 0, stream>>>(
      x, z0, wh_b0, hb0, nullptr, nullptr, nullptr);
  zx1_gemm_kernel<<<dim3((Bn*Tn)/64), dim3(256), 0, stream>>>(
      hb0, wx_b1, b_b1, z0);                    // z0 buffer reused as ZX1
  lstm_fast<false><<<dim3(Bn), dim3(256), 0, stream>>>(
      x, z0, wh_b1, hb0, dw, db, out);
}

// Round 10
// 630.745 us; speedup vs baseline: 1.0360x; 1.0360x over previous
//
#include <hip/hip_runtime.h>
#include <hip/hip_bf16.h>

#define Bn 64
#define Tn 512
#define En 128
#define Hn 64
#define Gn 256   // 4*H
#define Cn 20

__device__ __forceinline__ float sigf(float x)      { return 1.f/(1.f+__expf(-x)); }
__device__ __forceinline__ float tanhfast(float x)  { return 2.f/(1.f+__expf(-2.f*x)) - 1.f; }

// ---------------------------------------------------------------------------
// Kernel A: Z0[b*T+t][j] = (word_emb[ids[b,t]] + pos_emb[t]) @ Wx_b0 + b_b0
// ---------------------------------------------------------------------------
__global__ __launch_bounds__(256, 1) void emb_proj_kernel(
    const int* __restrict__ x, const float* __restrict__ word_emb,
    const float* __restrict__ pos_emb, const float* __restrict__ wx,
    const float* __restrict__ bias, float* __restrict__ z0)
{
  __shared__ float emb[64][En];     // 32 KB
  __shared__ float wxl[32][Gn];     // 32 KB
  const int tid  = threadIdx.x;
  const int row0 = blockIdx.x * 64;

  #pragma unroll
  for (int it = 0; it < 8; ++it) {
    int idx = it*256 + tid;
    int rr  = idx >> 5;
    int e4  = (idx & 31) << 2;
    int r   = row0 + rr;
    int b   = r >> 9;
    int t   = r & (Tn-1);
    int id  = x[b*3*Tn + t];
    float4 we = *reinterpret_cast<const float4*>(&word_emb[(size_t)id*En + e4]);
    float4 pe = *reinterpret_cast<const float4*>(&pos_emb[(size_t)t*En + e4]);
    *reinterpret_cast<float4*>(&emb[rr][e4]) =
        make_float4(we.x+pe.x, we.y+pe.y, we.z+pe.z, we.w+pe.w);
  }

  const int jc = tid & 63;
  const int rg = tid >> 6;
  float acc[16][4];
  float4 bb = *reinterpret_cast<const float4*>(&bias[jc*4]);
  #pragma unroll
  for (int r = 0; r < 16; ++r) { acc[r][0]=bb.x; acc[r][1]=bb.y; acc[r][2]=bb.z; acc[r][3]=bb.w; }

  for (int ec = 0; ec < 4; ++ec) {
    __syncthreads();
    #pragma unroll
    for (int it = 0; it < 8; ++it) {
      int idx = it*256 + tid;
      int ee  = idx >> 6;
      int j4  = (idx & 63) << 2;
      *reinterpret_cast<float4*>(&wxl[ee][j4]) =
          *reinterpret_cast<const float4*>(&wx[(size_t)(ec*32+ee)*Gn + j4]);
    }
    __syncthreads();
    for (int ee = 0; ee < 32; ++ee) {
      float4 w = *reinterpret_cast<const float4*>(&wxl[ee][jc*4]);
      #pragma unroll
      for (int r = 0; r < 16; ++r) {
        float xv = emb[rg*16+r][ec*32+ee];
        acc[r][0] = fmaf(xv, w.x, acc[r][0]);
        acc[r][1] = fmaf(xv, w.y, acc[r][1]);
        acc[r][2] = fmaf(xv, w.z, acc[r][2]);
        acc[r][3] = fmaf(xv, w.w, acc[r][3]);
      }
    }
  }
  #pragma unroll
  for (int r = 0; r < 16; ++r) {
    size_t row = (size_t)row0 + rg*16 + r;
    *reinterpret_cast<float4*>(&z0[row*Gn + jc*4]) =
        make_float4(acc[r][0], acc[r][1], acc[r][2], acc[r][3]);
  }
}

// ---------------------------------------------------------------------------
// Kernel A2: ZX1[b*T+t][j] = hb0[b,t,:] @ Wx_b1 + b_b1
// ---------------------------------------------------------------------------
__global__ __launch_bounds__(256, 1) void zx1_gemm_kernel(
    const float* __restrict__ hb0, const float* __restrict__ wx,
    const float* __restrict__ bias, float* __restrict__ zx1)
{
  __shared__ float xl[64][Hn];
  __shared__ float wl[32][Gn];
  const int tid  = threadIdx.x;
  const int row0 = blockIdx.x * 64;

  #pragma unroll
  for (int it = 0; it < 4; ++it) {
    int idx = it*256 + tid;
    int rr  = idx >> 4;
    int e4  = (idx & 15) << 2;
    *reinterpret_cast<float4*>(&xl[rr][e4]) =
        *reinterpret_cast<const float4*>(&hb0[((size_t)row0+rr)*Hn + e4]);
  }

  const int jc = tid & 63;
  const int rg = tid >> 6;
  float acc[16][4];
  float4 bb = *reinterpret_cast<const float4*>(&bias[jc*4]);
  #pragma unroll
  for (int r = 0; r < 16; ++r) { acc[r][0]=bb.x; acc[r][1]=bb.y; acc[r][2]=bb.z; acc[r][3]=bb.w; }

  for (int kc = 0; kc < 2; ++kc) {
    __syncthreads();
    #pragma unroll
    for (int it = 0; it < 8; ++it) {
      int idx = it*256 + tid;
      int kk  = idx >> 6;
      int j4  = (idx & 63) << 2;
      *reinterpret_cast<float4*>(&wl[kk][j4]) =
          *reinterpret_cast<const float4*>(&wx[(size_t)(kc*32+kk)*Gn + j4]);
    }
    __syncthreads();
    for (int kk = 0; kk < 32; ++kk) {
      float4 w = *reinterpret_cast<const float4*>(&wl[kk][jc*4]);
      #pragma unroll
      for (int r = 0; r < 16; ++r) {
        float xv = xl[rg*16+r][kc*32+kk];
        acc[r][0] = fmaf(xv, w.x, acc[r][0]);
        acc[r][1] = fmaf(xv, w.y, acc[r][1]);
        acc[r][2] = fmaf(xv, w.z, acc[r][2]);
        acc[r][3] = fmaf(xv, w.w, acc[r][3]);
      }
    }
  }
  #pragma unroll
  for (int r = 0; r < 16; ++r) {
    size_t row = (size_t)row0 + rg*16 + r;
    *reinterpret_cast<float4*>(&zx1[row*Gn + jc*4]) =
        make_float4(acc[r][0], acc[r][1], acc[r][2], acc[r][3]);
  }
}

// ---------------------------------------------------------------------------
// Recurrence: 256 threads / 4 waves per batch element. Thread tid owns gate
// column tid. The 64 weight floats are produced by inline-asm
// global_load_dword defs -- asm results cannot be rematerialized/re-executed
// by the compiler, forcing true VGPR residency (R6/R8/R9's VGPR_Count=52-56
// proved C-level loads get re-issued from memory every step because the
// in-loop "memory"-clobber asm invalidates memory-SSA). One raw s_barrier
// per step (lgkm-only drain); in-loop VMEM is asm with counted vmcnt.
// ---------------------------------------------------------------------------
#define WAVE_BARRIER()                                        \
  do {                                                        \
    asm volatile("s_waitcnt lgkmcnt(0)" ::: "memory");        \
    __builtin_amdgcn_sched_barrier(0);                        \
    __builtin_amdgcn_s_barrier();                             \
    __builtin_amdgcn_sched_barrier(0);                        \
  } while (0)

#define PLOAD(dst, t_)                                                      \
  { const float* pp_ = zr + (size_t)(t_)*Gn + tid;                          \
    asm volatile("global_load_dword %0, %1, off" : "=v"(dst) : "v"(pp_)); }

// group g: rows 4g..4g+3 of Wh, this thread's column, via ONE base pointer
// + byte offsets 0/1024/2048/3072 (13-bit signed imm limit is 4095).
#define DECLW(g)                                                            \
  float w##g##_0, w##g##_1, w##g##_2, w##g##_3;                             \
  { const float* pg_ = wh + (size_t)(4*(g))*Gn + tid;                       \
    asm volatile("global_load_dword %0, %4, off\n\t"                        \
                 "global_load_dword %1, %4, off offset:1024\n\t"            \
                 "global_load_dword %2, %4, off offset:2048\n\t"            \
                 "global_load_dword %3, %4, off offset:3072"                \
                 : "=v"(w##g##_0), "=v"(w##g##_1),                          \
                   "=v"(w##g##_2), "=v"(w##g##_3)                           \
                 : "v"(pg_)); }

// one 4-wide K-slice: h[4g..4g+3] (LDS b128 broadcast) * opaque weights
#define FMAK(g)                                                             \
  { float4 hv = *reinterpret_cast<const float4*>(&h_own[wv][(g)*4]);        \
    A0 = fmaf(hv.x, w##g##_0, A0);                                          \
    A1 = fmaf(hv.y, w##g##_1, A1);                                          \
    A2 = fmaf(hv.z, w##g##_2, A2);                                          \
    A3 = fmaf(hv.w, w##g##_3, A3); }

template<bool IS_B0>
__global__ __launch_bounds__(256, 1) void lstm_fast(
    const int* __restrict__ x, const float* __restrict__ z,
    const float* __restrict__ wh, float* __restrict__ hb0,
    const float* __restrict__ dw, const float* __restrict__ db,
    float* __restrict__ out)
{
  const int b   = blockIdx.x;
  const int tid = threadIdx.x;
  const int wv  = tid >> 6;
  const int l   = tid & 63;

  __shared__ __align__(16) float z_s[2][Gn];
  __shared__ __align__(16) float h_own[4][Hn];   // per-wave private h copy
  __shared__ float sm[2][32];
  __shared__ int slen;

  if (tid == 0) slen = 0;
  __syncthreads();
  {
    int m0 = x[b*3*Tn + 2*Tn + tid];
    int m1 = x[b*3*Tn + 2*Tn + 256 + tid];
    atomicAdd(&slen, m0 + m1);
  }
  h_own[wv][l] = 0.f;
  __syncthreads();
  const int len = slen;             // in [T/4, T]; mask is 1s then 0s

  const float* zr   = z   + (size_t)b*Tn*Gn;
  float*       hout = hb0 + (size_t)b*Tn*Hn;
  float c = 0.f, h = 0.f;

  if (IS_B0) {
    // rows [len, T-1] of hout must be 0 (b1 consumes them)
    for (int r = len + (tid >> 4); r < Tn; r += 16)
      *reinterpret_cast<float4*>(&hout[(size_t)r*Hn + (tid & 15)*4]) =
          make_float4(0.f, 0.f, 0.f, 0.f);
  }

  // 64 weight floats as inline-asm defs -> forced VGPR residency
  DECLW(0)  DECLW(1)  DECLW(2)  DECLW(3)
  DECLW(4)  DECLW(5)  DECLW(6)  DECLW(7)
  DECLW(8)  DECLW(9)  DECLW(10) DECLW(11)
  DECLW(12) DECLW(13) DECLW(14) DECLW(15)

  // depth-4 z prefetch into fixed named regs
  float zp0, zp1, zp2, zp3;
  PLOAD(zp0, IS_B0 ? len-1 : Tn-len);
  PLOAD(zp1, IS_B0 ? len-2 : Tn-len+1);
  PLOAD(zp2, IS_B0 ? len-3 : Tn-len+2);
  PLOAD(zp3, IS_B0 ? len-4 : Tn-len+3);
  // drain weights + prologue z + zero-fill stores ONCE
  asm volatile("s_waitcnt vmcnt(0)" ::: "memory");
  __builtin_amdgcn_sched_barrier(0);

#define STEP(s_, ZREG)                                                       \
  {                                                                          \
    if (IS_B0) asm volatile("s_waitcnt vmcnt(7)" ::: "memory");              \
    else       asm volatile("s_waitcnt vmcnt(3)" ::: "memory");              \
    __builtin_amdgcn_sched_barrier(0);                                       \
    float A0 = ZREG, A1 = 0.f, A2 = 0.f, A3 = 0.f;                           \
    FMAK(0)  FMAK(1)  FMAK(2)  FMAK(3)                                       \
    FMAK(4)  FMAK(5)  FMAK(6)  FMAK(7)                                       \
    FMAK(8)  FMAK(9)  FMAK(10) FMAK(11)                                      \
    FMAK(12) FMAK(13) FMAK(14) FMAK(15)                                      \
    z_s[(s_)&1][tid] = (A0+A1)+(A2+A3);                                      \
    { /* issue load for step s_+4 early (max slack) */                       \
      int tn_ = IS_B0 ? (len-5-(s_)) : (Tn-len+(s_)+4);                      \
      tn_ = tn_ < 0 ? 0 : (tn_ > Tn-1 ? Tn-1 : tn_);                         \
      const float* pp_ = zr + (size_t)tn_*Gn + tid;                          \
      asm volatile("global_load_dword %0, %1, off" : "=v"(ZREG) : "v"(pp_)); \
    }                                                                        \
    WAVE_BARRIER();                                                          \
    float g0 = z_s[(s_)&1][l],      g1 = z_s[(s_)&1][Hn+l];                  \
    float g2 = z_s[(s_)&1][2*Hn+l], g3 = z_s[(s_)&1][3*Hn+l];                \
    float ig = sigf(g0), fg = sigf(g1);                                      \
    float gg = tanhfast(g2), og = sigf(g3);                                  \
    float cn_ = fmaf(fg, c, ig*gg);                                          \
    float hn_ = og * tanhfast(cn_);                                          \
    bool act_ = (s_) < len;                                                  \
    c = act_ ? cn_ : c;                                                      \
    h = act_ ? hn_ : h;                                                      \
    h_own[wv][l] = h;                                                        \
    if (IS_B0) {                                                             \
      int ts_ = len-1-(s_); ts_ = ts_ < 0 ? 0 : ts_;                         \
      float* sp_ = hout + (size_t)ts_*Hn + l;                                \
      asm volatile("global_store_dword %0, %1, off" :: "v"(sp_), "v"(h));    \
    }                                                                        \
  }

  const int lenr = (len + 3) & ~3;
  for (int s = 0; s < lenr; s += 4) {
    STEP(s+0, zp0);
    STEP(s+1, zp1);
    STEP(s+2, zp2);
    STEP(s+3, zp3);
  }
#undef STEP

  // drain asm VMEM; keep async-written regs alive past the drain (R5 lesson)
  asm volatile("s_waitcnt vmcnt(0)" ::: "memory");
  asm volatile("" :: "v"(zp0), "v"(zp1), "v"(zp2), "v"(zp3));
  __builtin_amdgcn_sched_barrier(0);

  if (!IS_B0) {
    // head: logits (C=20) + softmax; wave-0 lanes, wave-synchronous LDS
    if (tid < Cn) {
      float lg = db[tid];
      #pragma unroll
      for (int k = 0; k < Hn; ++k) lg = fmaf(h_own[0][k], dw[k*Cn + tid], lg);
      sm[0][tid] = lg;
    }
    if (tid < Cn) {
      float m = sm[0][0];
      #pragma unroll
      for (int k = 1; k < Cn; ++k) m = fmaxf(m, sm[0][k]);
      float e = __expf(sm[0][tid] - m);
      sm[1][tid] = e;
      float ssum = 0.f;
      #pragma unroll
      for (int k = 0; k < Cn; ++k) ssum += sm[1][k];
      out[b*Cn + tid] = e / ssum;
    }
  }
}

// ---------------------------------------------------------------------------
extern "C" void kernel_launch(void* const* d_in, const int* in_sizes, int n_in,
                              void* d_out, int out_size, void* d_ws, size_t ws_size,
                              hipStream_t stream)
{
  const int*   x        = (const int*)  d_in[0];
  const float* word_emb = (const float*)d_in[1];
  const float* pos_emb  = (const float*)d_in[2];
  // forward-branch weights d_in[3..8] are dead code in the reference
  const float* wx_b0    = (const float*)d_in[9];
  const float* wh_b0    = (const float*)d_in[10];
  const float* b_b0     = (const float*)d_in[11];
  const float* wx_b1    = (const float*)d_in[12];
  const float* wh_b1    = (const float*)d_in[13];
  const float* b_b1     = (const float*)d_in[14];
  const float* dw       = (const float*)d_in[15];
  const float* db       = (const float*)d_in[16];
  float* out = (float*)d_out;

  float* z0  = (float*)d_ws;                    // B*T*256 f32 = 33.5 MB (reused as ZX1)
  float* hb0 = z0 + (size_t)Bn*Tn*Gn;           // B*T*64  f32 =  8.4 MB

  emb_proj_kernel<<<dim3((Bn*Tn)/64), dim3(256), 0, stream>>>(
      x, word_emb, pos_emb, wx_b0, b_b0, z0);
  lstm_fast<true><<<dim3(Bn), dim3(256), 0, stream>>>(
      x, z0, wh_b0, hb0, nullptr, nullptr, nullptr);
  zx1_gemm_kernel<<<dim3((Bn*Tn)/64), dim3(256), 0, stream>>>(
      hb0, wx_b1, b_b1, z0);                    // z0 buffer reused as ZX1
  lstm_fast<false><<<dim3(Bn), dim3(256), 0, stream>>>(
      x, z0, wh_b1, hb0, dw, db, out);
}